// Round 5
// baseline (167.174 us; speedup 1.0000x reference)
//
#include <hip/hip_runtime.h>
#include <stdint.h>
#include <stddef.h>

// GCCN: h1 = relu(x @ W1); h2 = relu(geo(h1, Wg1) + b1); res = geo(h2, Wg2) + b2; out = res/|res|
// geo(h, Wg)[n,o] = sum_b sum_i h[conn[n,b], i] * Wg[b,i,o]   (gathered GEMM, K = 80*64)
//
// Round-5 structure: split-K (4 chunks x 20 bins) -> f32 partials -> finalize.
// k_geo2: ALL 20 bin weight tiles resident in LDS (80KB, OT=2 cols; layer 1
// O-split via blockIdx.z), conn slice in LDS, ONE barrier total, fully unrolled
// bin loop with 6-bin-deep register gather prefetch, no per-bin barriers, no
// manual waitcnt (compiler inserts precise deps in straight-line code).

typedef __attribute__((ext_vector_type(8))) short bf16x8;
typedef __attribute__((ext_vector_type(4))) float f32x4;

#define BINS 80
#define SPLITK 4
#define BPC 20           // bins per chunk
#define PF 6             // gather prefetch depth (bins ahead)

static __device__ __forceinline__ unsigned short f2bf(float f) {
  union { float f; unsigned int u; } c; c.f = f;
  unsigned int u = c.u;
  return (unsigned short)((u + 0x7FFFu + ((u >> 16) & 1u)) >> 16);
}

// ---------------- linear_1: h1[v][64] = relu(x[v][0:16] @ W1) as bf16 ----------------
__global__ __launch_bounds__(256) void k_lin1(const float* __restrict__ x,
                                              const float* __restrict__ W1,
                                              unsigned short* __restrict__ h1b, int n) {
  __shared__ float w1s[16 * 64];
  int tid = threadIdx.x;
  for (int i = tid; i < 16 * 64; i += 256) w1s[i] = W1[i];
  __syncthreads();
  int v = blockIdx.x * 256 + tid;
  if (v >= n) return;
  const float4* xp = (const float4*)(x + (size_t)v * 16);
  float4 x0 = xp[0], x1 = xp[1], x2 = xp[2], x3 = xp[3];
  float xr[16] = {x0.x, x0.y, x0.z, x0.w, x1.x, x1.y, x1.z, x1.w,
                  x2.x, x2.y, x2.z, x2.w, x3.x, x3.y, x3.z, x3.w};
  float acc[64];
#pragma unroll
  for (int o = 0; o < 64; ++o) acc[o] = 0.f;
#pragma unroll
  for (int i = 0; i < 16; ++i) {
    float xi = xr[i];
#pragma unroll
    for (int o = 0; o < 64; ++o) acc[o] = fmaf(xi, w1s[i * 64 + o], acc[o]);
  }
  unsigned short* hr = h1b + (size_t)v * 64;
#pragma unroll
  for (int o8 = 0; o8 < 8; ++o8) {
    bf16x8 pack;
#pragma unroll
    for (int j = 0; j < 8; ++j) pack[j] = (short)f2bf(fmaxf(acc[o8 * 8 + j], 0.f));
    *(bf16x8*)(hr + o8 * 8) = pack;
  }
}

// ------ weight image: Wg[b][i][o] f32 -> img[b] rows o (128B of bf16 i), XOR-swizzled ------
// byte(o,i) = (o*128 + i*2) ^ ((o&7)<<4)   (swizzle is row-local; 32-row slabs stay intact)
__global__ __launch_bounds__(256) void k_wimg(const float* __restrict__ Wg,
                                              unsigned char* __restrict__ img,
                                              int O, int total) {
  int t = blockIdx.x * 256 + threadIdx.x;
  if (t >= total) return;                 // total = 80 * O * 8 chunk tasks
  int c = t & 7;                          // 16B chunk within row (8 i-values)
  int o = (t >> 3) % O;
  int b = t / (O * 8);
  int boff = (o * 128 + c * 16) ^ ((o & 7) << 4);
  bf16x8 pack;
#pragma unroll
  for (int j = 0; j < 8; ++j)
    pack[j] = (short)f2bf(Wg[(size_t)(b * 64 + c * 8 + j) * O + o]);
  *(bf16x8*)(img + (size_t)b * (O * 128) + boff) = pack;
}

// ---------------- geodesic layer: barrier-free bin loop, all weights in LDS ----------------
// grid (vt, SPLITK, OHALVES); block 512 = 8 waves; wave w owns rows [v0+w*32, +32) (2 m-tiles),
// output cols [z*32, +32). SRCT = bytes per bin in wimg (8192 L1 / 4096 L2); OSTR = part col stride.
template <int SRCT, int OSTR>
__global__ __launch_bounds__(512, 1) void k_geo2(const unsigned short* __restrict__ hin,
                                                 const unsigned char* __restrict__ wimg,
                                                 const int* __restrict__ conn,
                                                 float* __restrict__ part, int n) {
  __shared__ alignas(16) unsigned char wg_s[BPC * 4096];   // 80KB: 20 bins x (32 rows x 128B)
  __shared__ int conn_s[256 * BPC];                        // 20KB

  const int tid = threadIdx.x;
  const int lane = tid & 63;
  const int wave = tid >> 6;
  const int ln15 = lane & 15;
  const int lq = lane >> 4;               // 0..3
  const int v0 = blockIdx.x * 256;
  const int bin0 = blockIdx.y * BPC;
  const int zh = blockIdx.z;              // O-half (always 0 for layer 2)

  // stage conn slice: 256 rows x BPC ints, int4-vectorized (BPC/4 = 5 chunks/row)
  for (int t = tid; t < 256 * (BPC / 4); t += 512) {
    int v = t / (BPC / 4);
    int c4 = t - v * (BPC / 4);
    int vv = v0 + v;
    if (vv > n - 1) vv = n - 1;
    int4 q = *(const int4*)(conn + (size_t)vv * BINS + bin0 + c4 * 4);
    *(int4*)(&conn_s[v * BPC + c4 * 4]) = q;
  }

  // stage all 20 weight tiles (this block's 32-col slab of each bin) into linear LDS.
  // LDS dst = wave-uniform base + lane*16 (required by global_load_lds); src per-lane.
  {
    const unsigned char* wsrc = wimg + (size_t)bin0 * SRCT + (size_t)zh * 4096;
#pragma unroll
    for (int r = 0; r < 10; ++r) {                 // 10 * 512 * 16B = 80KB exactly
      int off = (r * 512 + tid) * 16;
      int bin = off >> 12;
      int within = off & 4095;
      __builtin_amdgcn_global_load_lds(
          (const __attribute__((address_space(1))) unsigned int*)(const void*)(wsrc + (size_t)bin * SRCT + within),
          (__attribute__((address_space(3))) unsigned int*)(void*)(wg_s + off),
          16, 0, 0);
    }
  }
  __syncthreads();   // single barrier: drains staging (vmcnt+lgkm), conn_s + wg_s ready

  // per-lane swizzled B-fragment byte offsets (local row o' = ot*16+ln15; (o'&7)==(o&7))
  int boffs[2][2];
#pragma unroll
  for (int ot = 0; ot < 2; ++ot)
#pragma unroll
    for (int s = 0; s < 2; ++s) {
      int o = ot * 16 + ln15;
      boffs[ot][s] = (o * 128 + s * 64 + lq * 16) ^ ((o & 7) << 4);
    }

  const int crow0 = (wave * 32 + ln15) * BPC;      // mt0 conn row base
  const int crow1 = crow0 + 16 * BPC;              // mt1
  const int koff = lq * 8;

  bf16x8 As[8][2][2];                              // [b&7][mt][k-half], static after unroll
  f32x4 acc[2][2];
#pragma unroll
  for (int mt = 0; mt < 2; ++mt)
#pragma unroll
    for (int ot = 0; ot < 2; ++ot) acc[mt][ot] = (f32x4){0.f, 0.f, 0.f, 0.f};

#define ISSUE(j)                                                        \
  {                                                                     \
    int c0 = conn_s[crow0 + (j)];                                       \
    int c1 = conn_s[crow1 + (j)];                                       \
    const unsigned short* r0 = hin + (size_t)c0 * 64 + koff;            \
    const unsigned short* r1 = hin + (size_t)c1 * 64 + koff;            \
    As[(j) & 7][0][0] = *(const bf16x8*)(r0);                           \
    As[(j) & 7][0][1] = *(const bf16x8*)(r0 + 32);                      \
    As[(j) & 7][1][0] = *(const bf16x8*)(r1);                           \
    As[(j) & 7][1][1] = *(const bf16x8*)(r1 + 32);                      \
  }

#pragma unroll
  for (int j = 0; j < PF; ++j) ISSUE(j);

#pragma unroll
  for (int b = 0; b < BPC; ++b) {
    if (b + PF < BPC) ISSUE(b + PF);
    const unsigned char* wb = wg_s + b * 4096;
#pragma unroll
    for (int ot = 0; ot < 2; ++ot) {
      bf16x8 b0 = *(const bf16x8*)(wb + boffs[ot][0]);
      bf16x8 b1 = *(const bf16x8*)(wb + boffs[ot][1]);
#pragma unroll
      for (int mt = 0; mt < 2; ++mt) {
        acc[mt][ot] = __builtin_amdgcn_mfma_f32_16x16x32_bf16(As[b & 7][mt][0], b0,
                                                              acc[mt][ot], 0, 0, 0);
        acc[mt][ot] = __builtin_amdgcn_mfma_f32_16x16x32_bf16(As[b & 7][mt][1], b1,
                                                              acc[mt][ot], 0, 0, 0);
      }
    }
  }
#undef ISSUE

  // write f32 partials: part[(chunk*n + v)*OSTR + zh*32 + o']; C/D: col=ln15, row=lq*4+r
  float* pbase = part + (size_t)blockIdx.y * n * OSTR + zh * 32;
#pragma unroll
  for (int mt = 0; mt < 2; ++mt)
#pragma unroll
    for (int ot = 0; ot < 2; ++ot)
#pragma unroll
      for (int r = 0; r < 4; ++r) {
        int v = v0 + wave * 32 + mt * 16 + lq * 4 + r;
        if (v < n) pbase[(size_t)v * OSTR + ot * 16 + ln15] = acc[mt][ot][r];
      }
}

// ---------------- finalize GC1: sum 4 partials + bias, relu, bf16 ----------------
__global__ __launch_bounds__(256) void k_fin1(const float* __restrict__ part,
                                              const float* __restrict__ bias,
                                              unsigned short* __restrict__ out, int n) {
  int t = blockIdx.x * 256 + threadIdx.x;
  int total = n * 16;                     // groups of 4 outputs
  if (t >= total) return;
  int base = t * 4;
  int o = base & 63;
  size_t stride = (size_t)n * 64;
  const float* p = part + base;
  float4 s = *(const float4*)(p);
#pragma unroll
  for (int c = 1; c < SPLITK; ++c) {
    float4 q = *(const float4*)(p + c * stride);
    s.x += q.x; s.y += q.y; s.z += q.z; s.w += q.w;
  }
  float4 b4 = *(const float4*)(bias + o);
  ushort4 pack;
  pack.x = f2bf(fmaxf(s.x + b4.x, 0.f));
  pack.y = f2bf(fmaxf(s.y + b4.y, 0.f));
  pack.z = f2bf(fmaxf(s.z + b4.z, 0.f));
  pack.w = f2bf(fmaxf(s.w + b4.w, 0.f));
  *(ushort4*)(out + base) = pack;
}

// ---------------- finalize GC2: sum 4 partials + bias, normalize ----------------
__global__ __launch_bounds__(256) void k_fin2(const float* __restrict__ part,
                                              const float* __restrict__ bias,
                                              float* __restrict__ out, int n) {
  int v = blockIdx.x * 16 + (threadIdx.x >> 4);
  int o = threadIdx.x & 15;
  if (v >= n) return;
  size_t stride = (size_t)n * 32;
  const float* p = part + (size_t)v * 32 + o;
  float a = 0.f, b = 0.f;
#pragma unroll
  for (int c = 0; c < SPLITK; ++c) {
    a += p[c * stride];
    b += p[c * stride + 16];
  }
  a += bias[o];
  b += bias[o + 16];
  float ss = a * a + b * b;
  ss += __shfl_xor(ss, 1);
  ss += __shfl_xor(ss, 2);
  ss += __shfl_xor(ss, 4);
  ss += __shfl_xor(ss, 8);
  float inv = 1.0f / sqrtf(ss);
  out[(size_t)v * 32 + o] = a * inv;
  out[(size_t)v * 32 + 16 + o] = b * inv;
}

extern "C" void kernel_launch(void* const* d_in, const int* in_sizes, int n_in,
                              void* d_out, int out_size, void* d_ws, size_t ws_size,
                              hipStream_t stream) {
  const float* x   = (const float*)d_in[0];
  const float* W1  = (const float*)d_in[1];
  const float* Wg1 = (const float*)d_in[2];
  const float* b1  = (const float*)d_in[3];
  const float* Wg2 = (const float*)d_in[4];
  const float* b2  = (const float*)d_in[5];
  const int*  conn = (const int*)d_in[6];
  int n = in_sizes[0] / 16;

  unsigned char* ws = (unsigned char*)d_ws;
  size_t hb = ((size_t)n * 64 * 2 + 255) & ~(size_t)255;   // bf16 h table bytes
  unsigned short* h1b = (unsigned short*)(ws);
  unsigned short* h2b = (unsigned short*)(ws + hb);
  unsigned char*  w1i = ws + 2 * hb;                        // 80 * 8192
  unsigned char*  w2i = ws + 2 * hb + 80 * 8192;            // 80 * 4096
  float* part = (float*)(ws + 2 * hb + 80 * 8192 + 80 * 4096);  // SPLITK*n*64 f32

  k_wimg<<<(80 * 64 * 8 + 255) / 256, 256, 0, stream>>>(Wg1, w1i, 64, 80 * 64 * 8);
  k_wimg<<<(80 * 32 * 8 + 255) / 256, 256, 0, stream>>>(Wg2, w2i, 32, 80 * 32 * 8);
  k_lin1<<<(n + 255) / 256, 256, 0, stream>>>(x, W1, h1b, n);

  int vt = (n + 255) / 256;
  k_geo2<8192, 64><<<dim3(vt, SPLITK, 2), 512, 0, stream>>>(h1b, w1i, conn, part, n);
  k_fin1<<<(n * 16 + 255) / 256, 256, 0, stream>>>(part, b1, h2b, n);
  k_geo2<4096, 32><<<dim3(vt, SPLITK, 1), 512, 0, stream>>>(h2b, w2i, conn, part, n);
  k_fin2<<<(n + 15) / 16, 256, 0, stream>>>(part, b2, (float*)d_out, n);
}

// Round 6
// 131.700 us; speedup vs baseline: 1.2694x; 1.2694x over previous
//
#include <hip/hip_runtime.h>
#include <stdint.h>
#include <stddef.h>

// GCCN: h1 = relu(x @ W1); h2 = relu(geo(h1, Wg1) + b1); res = geo(h2, Wg2) + b2; out = res/|res|
// geo(h, Wg)[n,o] = sum_b sum_i h[conn[n,b], i] * Wg[b,i,o]   (gathered GEMM, K = 80*64)
//
// Round-6: split-K (4 chunks x 20 bins) -> f32 partials -> finalize.
// k_geo3: per block, TWO i-half phases (z=0: i 0..31, z=1: i 32..63) over the same
// 20 bins; all 20 per-phase weight slabs in LDS (restaged between phases).
// Gathers are asm-volatile global_load_dwordx4 into pinned registers, 6 bins deep,
// with manually counted s_waitcnt vmcnt(N) (+sched_barrier(0), rule #18).

typedef __attribute__((ext_vector_type(8))) short bf16x8;
typedef __attribute__((ext_vector_type(4))) float f32x4;

#define BINS 80
#define SPLITK 4
#define BPC 20           // bins per chunk
#define PF 6             // gather prefetch depth (bins ahead)

static __device__ __forceinline__ unsigned short f2bf(float f) {
  union { float f; unsigned int u; } c; c.f = f;
  unsigned int u = c.u;
  return (unsigned short)((u + 0x7FFFu + ((u >> 16) & 1u)) >> 16);
}

static __device__ __forceinline__ void wait_vm(int m) {
  // constant-folds after full unroll; literal asm per count
  if (m >= 12)      asm volatile("s_waitcnt vmcnt(12)");
  else if (m == 10) asm volatile("s_waitcnt vmcnt(10)");
  else if (m == 8)  asm volatile("s_waitcnt vmcnt(8)");
  else if (m == 6)  asm volatile("s_waitcnt vmcnt(6)");
  else if (m == 4)  asm volatile("s_waitcnt vmcnt(4)");
  else if (m == 2)  asm volatile("s_waitcnt vmcnt(2)");
  else              asm volatile("s_waitcnt vmcnt(0)");
}

// ---------------- linear_1: h1[v][64] = relu(x[v][0:16] @ W1) as bf16 ----------------
__global__ __launch_bounds__(256) void k_lin1(const float* __restrict__ x,
                                              const float* __restrict__ W1,
                                              unsigned short* __restrict__ h1b, int n) {
  __shared__ float w1s[16 * 64];
  int tid = threadIdx.x;
  for (int i = tid; i < 16 * 64; i += 256) w1s[i] = W1[i];
  __syncthreads();
  int v = blockIdx.x * 256 + tid;
  if (v >= n) return;
  const float4* xp = (const float4*)(x + (size_t)v * 16);
  float4 x0 = xp[0], x1 = xp[1], x2 = xp[2], x3 = xp[3];
  float xr[16] = {x0.x, x0.y, x0.z, x0.w, x1.x, x1.y, x1.z, x1.w,
                  x2.x, x2.y, x2.z, x2.w, x3.x, x3.y, x3.z, x3.w};
  float acc[64];
#pragma unroll
  for (int o = 0; o < 64; ++o) acc[o] = 0.f;
#pragma unroll
  for (int i = 0; i < 16; ++i) {
    float xi = xr[i];
#pragma unroll
    for (int o = 0; o < 64; ++o) acc[o] = fmaf(xi, w1s[i * 64 + o], acc[o]);
  }
  unsigned short* hr = h1b + (size_t)v * 64;
#pragma unroll
  for (int o8 = 0; o8 < 8; ++o8) {
    bf16x8 pack;
#pragma unroll
    for (int j = 0; j < 8; ++j) pack[j] = (short)f2bf(fmaxf(acc[o8 * 8 + j], 0.f));
    *(bf16x8*)(hr + o8 * 8) = pack;
  }
}

// ---- weight image: Wg[b][i][o] f32 -> img[b][z][o][chunk] bf16, chunk-permuted ----
// byte(b,z,o,j) = b*(O*128) + z*(O*64) + o*64 + ((j+(o>>1))&3)*16
// holds Wg[b][z*32 + j*8 .. +8][o].  Reader uses chunk ((lq+(o>>1))&3) -> 2-way banks.
__global__ __launch_bounds__(256) void k_wimg(const float* __restrict__ Wg,
                                              unsigned char* __restrict__ img,
                                              int O, int total) {
  int t = blockIdx.x * 256 + threadIdx.x;
  if (t >= total) return;                 // total = 80 * 2 * O * 4
  int j = t & 3;
  int r = t >> 2;
  int o = r % O;
  int r2 = r / O;
  int z = r2 & 1;
  int b = r2 >> 1;
  bf16x8 pack;
#pragma unroll
  for (int tt = 0; tt < 8; ++tt)
    pack[tt] = (short)f2bf(Wg[(size_t)(b * 64 + z * 32 + j * 8 + tt) * O + o]);
  size_t boff = (size_t)b * (O * 128) + z * (O * 64) + o * 64 + ((j + (o >> 1)) & 3) * 16;
  *(bf16x8*)(img + boff) = pack;
}

// ---------------- geodesic layer: i-half phases, pinned-register gather pipeline ----------------
// grid (vt, SPLITK); block 512 = 8 waves; wave w owns rows [v0+w*32, +32) (2 m-tiles), all O cols.
template <int OT>   // O = OT*16; per-bin per-phase slab = OT*1024 bytes
__global__ __launch_bounds__(512, 1) void k_geo3(const unsigned short* __restrict__ hin,
                                                 const unsigned char* __restrict__ wimg,
                                                 const int* __restrict__ conn,
                                                 float* __restrict__ part, int n) {
  constexpr int SLAB = OT * 1024;
  constexpr int R = (BPC * SLAB) / 8192;      // staging rounds (512 thr x 16B)
  __shared__ alignas(16) unsigned char wg_s[BPC * SLAB];
  __shared__ int conn_s[256 * 21];

  const int tid = threadIdx.x;
  const int lane = tid & 63;
  const int wave = tid >> 6;
  const int ln15 = lane & 15;
  const int lq = lane >> 4;                   // 0..3
  const int v0 = blockIdx.x * 256;
  const int chunk = blockIdx.y;
  const int bin0 = chunk * BPC;

  // stage conn slice (scalar; once per block)
  for (int t = tid; t < 256 * BPC; t += 512) {
    int v = t / BPC, c = t - v * BPC;
    int vv = v0 + v;
    if (vv > n - 1) vv = n - 1;
    conn_s[v * 21 + c] = conn[(size_t)vv * BINS + bin0 + c];
  }

  auto stage = [&](int ph) {
#pragma unroll
    for (int r = 0; r < R; ++r) {
      int off = (r * 512 + tid) * 16;
      int bin = off / SLAB;
      int within = off & (SLAB - 1);
      __builtin_amdgcn_global_load_lds(
          (const __attribute__((address_space(1))) unsigned int*)(const void*)
              (wimg + (size_t)(bin0 + bin) * (2 * SLAB) + ph * SLAB + within),
          (__attribute__((address_space(3))) unsigned int*)(void*)(wg_s + off),
          16, 0, 0);
    }
  };

  // per-lane B-fragment byte offsets (chunk-permuted; constant across bins/phases)
  int boffs[OT];
#pragma unroll
  for (int ot = 0; ot < OT; ++ot) {
    int o = ot * 16 + ln15;
    boffs[ot] = o * 64 + ((lq + (o >> 1)) & 3) * 16;
  }

  const int crow0 = (wave * 32 + ln15) * 21;
  const int crow1 = crow0 + 16 * 21;
  const int koff = lq * 8;                    // elements within the 32-i half

  bf16x8 As[8][2];                            // pinned by asm outputs; reuse distance 8 > PF+1
  f32x4 acc[2][OT];
#pragma unroll
  for (int mt = 0; mt < 2; ++mt)
#pragma unroll
    for (int ot = 0; ot < OT; ++ot) acc[mt][ot] = (f32x4){0.f, 0.f, 0.f, 0.f};

#define ISSUE(ph, j) do {                                                        \
    int c0_ = conn_s[crow0 + (j)];                                               \
    int c1_ = conn_s[crow1 + (j)];                                               \
    const void* p0_ = (const void*)(hin + (size_t)c0_ * 64 + (ph) * 32 + koff);  \
    const void* p1_ = (const void*)(hin + (size_t)c1_ * 64 + (ph) * 32 + koff);  \
    asm volatile("global_load_dwordx4 %0, %1, off" : "=v"(As[(j) & 7][0]) : "v"(p0_)); \
    asm volatile("global_load_dwordx4 %0, %1, off" : "=v"(As[(j) & 7][1]) : "v"(p1_)); \
  } while (0)

  auto run_phase = [&](int ph) {
#pragma unroll
    for (int b = 0; b < BPC; ++b) {
      if (b + PF < BPC) ISSUE(ph, b + PF);
      int rem = BPC - 1 - b;
      wait_vm(2 * (rem > PF ? PF : rem));     // bin b's 2 loads retired; deeper stay in flight
      __builtin_amdgcn_sched_barrier(0);      // rule #18: nothing hoists above the wait
      const unsigned char* wb = wg_s + b * SLAB;
#pragma unroll
      for (int ot = 0; ot < OT; ++ot) {
        bf16x8 bf = *(const bf16x8*)(wb + boffs[ot]);
        acc[0][ot] = __builtin_amdgcn_mfma_f32_16x16x32_bf16(As[b & 7][0], bf, acc[0][ot], 0, 0, 0);
        acc[1][ot] = __builtin_amdgcn_mfma_f32_16x16x32_bf16(As[b & 7][1], bf, acc[1][ot], 0, 0, 0);
      }
    }
  };

  // ---- phase 0 ----
  stage(0);
  __syncthreads();                            // conn_s + wg_s(z0) ready (full drain)
#pragma unroll
  for (int j = 0; j < PF; ++j) ISSUE(0, j);
  run_phase(0);

  // ---- transition: all waves done reading wg_s(z0); restage z1 ----
  asm volatile("s_waitcnt lgkmcnt(0)" ::: "memory");
  __builtin_amdgcn_s_barrier();
  __builtin_amdgcn_sched_barrier(0);
  stage(1);
#pragma unroll
  for (int j = 0; j < PF; ++j) ISSUE(1, j);
  asm volatile("s_waitcnt vmcnt(0)" ::: "memory");   // staging + prefetch drained (once/block)
  __builtin_amdgcn_s_barrier();
  __builtin_amdgcn_sched_barrier(0);
  run_phase(1);
#undef ISSUE

  // write f32 partials: piece = chunk; C/D layout col=ln15, row=lq*4+r
  constexpr int O = OT * 16;
  float* pbase = part + (size_t)chunk * n * O;
#pragma unroll
  for (int mt = 0; mt < 2; ++mt)
#pragma unroll
    for (int ot = 0; ot < OT; ++ot)
#pragma unroll
      for (int r = 0; r < 4; ++r) {
        int v = v0 + wave * 32 + mt * 16 + lq * 4 + r;
        if (v < n) pbase[(size_t)v * O + ot * 16 + ln15] = acc[mt][ot][r];
      }
}

// ---------------- finalize GC1: sum 4 partials + bias, relu, bf16 ----------------
__global__ __launch_bounds__(256) void k_fin1(const float* __restrict__ part,
                                              const float* __restrict__ bias,
                                              unsigned short* __restrict__ out, int n) {
  int t = blockIdx.x * 256 + threadIdx.x;
  int total = n * 16;                     // groups of 4 outputs
  if (t >= total) return;
  int base = t * 4;
  int o = base & 63;
  size_t stride = (size_t)n * 64;
  const float* p = part + base;
  float4 s = *(const float4*)(p);
#pragma unroll
  for (int c = 1; c < SPLITK; ++c) {
    float4 q = *(const float4*)(p + c * stride);
    s.x += q.x; s.y += q.y; s.z += q.z; s.w += q.w;
  }
  float4 b4 = *(const float4*)(bias + o);
  ushort4 pack;
  pack.x = f2bf(fmaxf(s.x + b4.x, 0.f));
  pack.y = f2bf(fmaxf(s.y + b4.y, 0.f));
  pack.z = f2bf(fmaxf(s.z + b4.z, 0.f));
  pack.w = f2bf(fmaxf(s.w + b4.w, 0.f));
  *(ushort4*)(out + base) = pack;
}

// ---------------- finalize GC2: sum 4 partials + bias, normalize ----------------
__global__ __launch_bounds__(256) void k_fin2(const float* __restrict__ part,
                                              const float* __restrict__ bias,
                                              float* __restrict__ out, int n) {
  int v = blockIdx.x * 16 + (threadIdx.x >> 4);
  int o = threadIdx.x & 15;
  if (v >= n) return;
  size_t stride = (size_t)n * 32;
  const float* p = part + (size_t)v * 32 + o;
  float a = 0.f, b = 0.f;
#pragma unroll
  for (int c = 0; c < SPLITK; ++c) {
    a += p[c * stride];
    b += p[c * stride + 16];
  }
  a += bias[o];
  b += bias[o + 16];
  float ss = a * a + b * b;
  ss += __shfl_xor(ss, 1);
  ss += __shfl_xor(ss, 2);
  ss += __shfl_xor(ss, 4);
  ss += __shfl_xor(ss, 8);
  float inv = 1.0f / sqrtf(ss);
  out[(size_t)v * 32 + o] = a * inv;
  out[(size_t)v * 32 + 16 + o] = b * inv;
}

extern "C" void kernel_launch(void* const* d_in, const int* in_sizes, int n_in,
                              void* d_out, int out_size, void* d_ws, size_t ws_size,
                              hipStream_t stream) {
  const float* x   = (const float*)d_in[0];
  const float* W1  = (const float*)d_in[1];
  const float* Wg1 = (const float*)d_in[2];
  const float* b1  = (const float*)d_in[3];
  const float* Wg2 = (const float*)d_in[4];
  const float* b2  = (const float*)d_in[5];
  const int*  conn = (const int*)d_in[6];
  int n = in_sizes[0] / 16;

  unsigned char* ws = (unsigned char*)d_ws;
  size_t hb = ((size_t)n * 64 * 2 + 255) & ~(size_t)255;   // bf16 h table bytes
  unsigned short* h1b = (unsigned short*)(ws);
  unsigned short* h2b = (unsigned short*)(ws + hb);
  unsigned char*  w1i = ws + 2 * hb;                        // 80 * 8192
  unsigned char*  w2i = ws + 2 * hb + 80 * 8192;            // 80 * 4096
  float* part = (float*)(ws + 2 * hb + 80 * 8192 + 80 * 4096);  // SPLITK*n*64 f32

  k_wimg<<<(80 * 2 * 64 * 4 + 255) / 256, 256, 0, stream>>>(Wg1, w1i, 64, 80 * 2 * 64 * 4);
  k_wimg<<<(80 * 2 * 32 * 4 + 255) / 256, 256, 0, stream>>>(Wg2, w2i, 32, 80 * 2 * 32 * 4);
  k_lin1<<<(n + 255) / 256, 256, 0, stream>>>(x, W1, h1b, n);

  int vt = (n + 255) / 256;
  k_geo3<4><<<dim3(vt, SPLITK), 512, 0, stream>>>(h1b, w1i, conn, part, n);
  k_fin1<<<(n * 16 + 255) / 256, 256, 0, stream>>>(part, b1, h2b, n);
  k_geo3<2><<<dim3(vt, SPLITK), 512, 0, stream>>>(h2b, w2i, conn, part, n);
  k_fin2<<<(n + 15) / 16, 256, 0, stream>>>(part, b2, (float*)d_out, n);
}